// Round 1
// baseline (1496.753 us; speedup 1.0000x reference)
//
#include <hip/hip_runtime.h>
#include <cstddef>

#define N_NODES 100000
#define N_EDGES 1600000
#define DIM 128
#define LN_EPS 1e-5f

// ---------------- CSR build ----------------

__global__ void hist_kernel(const int* __restrict__ dst, int* __restrict__ deg, int e) {
    int i = blockIdx.x * blockDim.x + threadIdx.x;
    if (i < e) atomicAdd(&deg[dst[i]], 1);
}

// Single-block exclusive scan over n ints. Input degrees live in `cursor`;
// writes row_ptr[0..n] and resets cursor[i] = row_ptr[i] (running offsets).
__global__ __launch_bounds__(1024) void scan_kernel(int* __restrict__ cursor,
                                                    int* __restrict__ row_ptr, int n) {
    __shared__ int wsum[16];
    __shared__ int woff[16];
    __shared__ int ctot_s;
    const int tid = threadIdx.x;
    const int lane = tid & 63;
    const int wid = tid >> 6;
    int carry = 0;
    for (int base = 0; base < n; base += 4096) {
        const int i0 = base + tid * 4;
        int v0 = (i0 + 0 < n) ? cursor[i0 + 0] : 0;
        int v1 = (i0 + 1 < n) ? cursor[i0 + 1] : 0;
        int v2 = (i0 + 2 < n) ? cursor[i0 + 2] : 0;
        int v3 = (i0 + 3 < n) ? cursor[i0 + 3] : 0;
        const int tsum = v0 + v1 + v2 + v3;
        int incl = tsum;
        #pragma unroll
        for (int off = 1; off < 64; off <<= 1) {
            int t = __shfl_up(incl, off);
            if (lane >= off) incl += t;
        }
        if (lane == 63) wsum[wid] = incl;
        __syncthreads();
        if (wid == 0) {
            int x = (lane < 16) ? wsum[lane] : 0;
            int inc2 = x;
            #pragma unroll
            for (int off = 1; off < 16; off <<= 1) {
                int t = __shfl_up(inc2, off);
                if (lane >= off) inc2 += t;
            }
            if (lane < 16) woff[lane] = inc2 - x;
            if (lane == 15) ctot_s = inc2;
        }
        __syncthreads();
        int e0 = carry + woff[wid] + (incl - tsum);
        int e1 = e0 + v0;
        int e2 = e1 + v1;
        int e3 = e2 + v2;
        if (i0 + 0 < n) { row_ptr[i0 + 0] = e0; cursor[i0 + 0] = e0; }
        if (i0 + 1 < n) { row_ptr[i0 + 1] = e1; cursor[i0 + 1] = e1; }
        if (i0 + 2 < n) { row_ptr[i0 + 2] = e2; cursor[i0 + 2] = e2; }
        if (i0 + 3 < n) { row_ptr[i0 + 3] = e3; cursor[i0 + 3] = e3; }
        carry += ctot_s;
        __syncthreads();   // protect wsum/woff/ctot before next chunk overwrites
    }
    if (tid == 0) row_ptr[n] = carry;
}

__global__ void fill_kernel(const int* __restrict__ src, const int* __restrict__ dst,
                            int* __restrict__ cursor, int* __restrict__ col, int e) {
    int i = blockIdx.x * blockDim.x + threadIdx.x;
    if (i < e) {
        int p = atomicAdd(&cursor[dst[i]], 1);
        col[p] = src[i];
    }
}

// ---------------- aggregation (pull, one wave per node) ----------------

__global__ __launch_bounds__(256) void pull_kernel(const float* __restrict__ h,
                                                   const int* __restrict__ row_ptr,
                                                   const int* __restrict__ col,
                                                   float* __restrict__ agg, int n) {
    const int wid = threadIdx.x >> 6;
    const int lane = threadIdx.x & 63;
    const int node = blockIdx.x * 4 + wid;
    if (node >= n) return;
    const int beg = row_ptr[node];
    const int end = row_ptr[node + 1];
    float2 a0 = {0.f, 0.f}, a1 = {0.f, 0.f}, a2 = {0.f, 0.f}, a3 = {0.f, 0.f};
    int j = beg;
    for (; j + 4 <= end; j += 4) {
        int s0 = col[j + 0], s1 = col[j + 1], s2 = col[j + 2], s3 = col[j + 3];
        float2 p0 = *(const float2*)&h[(size_t)s0 * DIM + 2 * lane];
        float2 p1 = *(const float2*)&h[(size_t)s1 * DIM + 2 * lane];
        float2 p2 = *(const float2*)&h[(size_t)s2 * DIM + 2 * lane];
        float2 p3 = *(const float2*)&h[(size_t)s3 * DIM + 2 * lane];
        a0.x += p0.x; a0.y += p0.y;
        a1.x += p1.x; a1.y += p1.y;
        a2.x += p2.x; a2.y += p2.y;
        a3.x += p3.x; a3.y += p3.y;
    }
    for (; j < end; ++j) {
        int s = col[j];
        float2 p = *(const float2*)&h[(size_t)s * DIM + 2 * lane];
        a0.x += p.x; a0.y += p.y;
    }
    float2 r;
    r.x = (a0.x + a1.x) + (a2.x + a3.x);
    r.y = (a0.y + a1.y) + (a2.y + a3.y);
    *(float2*)&agg[(size_t)node * DIM + 2 * lane] = r;
}

// ---------------- fused GEMM + epilogue ----------------
// out = agg @ Wrel + brel + hprev @ Wroot  [+ hprev if MODE==1]
// MODE 0: relu + LN          (first layer)
// MODE 1: +residual, relu+LN (middle layers)
// MODE 2: plain              (last layer)

template <int MODE>
__global__ __launch_bounds__(256) void gemm_kernel(const float* __restrict__ agg,
                                                   const float* __restrict__ hprev,
                                                   const float* __restrict__ Wrel,
                                                   const float* __restrict__ brel,
                                                   const float* __restrict__ Wroot,
                                                   const float* __restrict__ gamma,
                                                   const float* __restrict__ beta,
                                                   float* __restrict__ out) {
    __shared__ float sAgg[16][DIM];
    __shared__ float sH[16][DIM];
    const int tid = threadIdx.x;
    const int row0 = blockIdx.x * 16;
    // stage 16 agg rows + 16 h rows (float4)
    for (int t = tid; t < 512; t += 256) {
        int r = t >> 5;
        int c = (t & 31) << 2;
        *(float4*)&sAgg[r][c] = *(const float4*)&agg[(size_t)(row0 + r) * DIM + c];
        *(float4*)&sH[r][c]   = *(const float4*)&hprev[(size_t)(row0 + r) * DIM + c];
    }
    __syncthreads();

    const int lane = tid & 63;
    const int w = tid >> 6;
    const int rb = w * 4;   // this wave owns local rows rb..rb+3
    const float2* wrp = (const float2*)Wrel + lane;
    const float2* wtp = (const float2*)Wroot + lane;

    float2 acc[4];
    #pragma unroll
    for (int r = 0; r < 4; ++r) { acc[r].x = 0.f; acc[r].y = 0.f; }

    for (int k = 0; k < DIM; k += 4) {
        float2 wr[4], wt[4];
        #pragma unroll
        for (int u = 0; u < 4; ++u) {
            wr[u] = wrp[(k + u) * 64];
            wt[u] = wtp[(k + u) * 64];
        }
        #pragma unroll
        for (int u = 0; u < 4; ++u) {
            #pragma unroll
            for (int r = 0; r < 4; ++r) {
                float a = sAgg[rb + r][k + u];
                float x = sH[rb + r][k + u];
                acc[r].x += a * wr[u].x + x * wt[u].x;
                acc[r].y += a * wr[u].y + x * wt[u].y;
            }
        }
    }

    const float2 bb = *(const float2*)&brel[2 * lane];
    const float2 gg = *(const float2*)&gamma[2 * lane];
    const float2 be = *(const float2*)&beta[2 * lane];

    #pragma unroll
    for (int r = 0; r < 4; ++r) {
        const int lrow = rb + r;
        float2 v = acc[r];
        v.x += bb.x; v.y += bb.y;
        if (MODE == 1) {
            float2 h2 = *(const float2*)&sH[lrow][2 * lane];
            v.x += h2.x; v.y += h2.y;
        }
        if (MODE != 2) {
            v.x = fmaxf(v.x, 0.f);
            v.y = fmaxf(v.y, 0.f);
            float s = v.x + v.y;
            float q = v.x * v.x + v.y * v.y;
            #pragma unroll
            for (int m = 32; m >= 1; m >>= 1) {
                s += __shfl_xor(s, m);
                q += __shfl_xor(q, m);
            }
            float mu = s * (1.f / DIM);
            float var = q * (1.f / DIM) - mu * mu;
            float rinv = rsqrtf(var + LN_EPS);
            v.x = (v.x - mu) * rinv * gg.x + be.x;
            v.y = (v.y - mu) * rinv * gg.y + be.y;
        }
        *(float2*)&out[(size_t)(row0 + lrow) * DIM + 2 * lane] = v;
    }
}

// ---------------- launch ----------------

static inline size_t align256(size_t x) { return (x + 255) & ~(size_t)255; }

extern "C" void kernel_launch(void* const* d_in, const int* in_sizes, int n_in,
                              void* d_out, int out_size, void* d_ws, size_t ws_size,
                              hipStream_t stream) {
    const float* in_feat = (const float*)d_in[0];
    const int*   ei      = (const int*)d_in[1];
    const float* Wrel    = (const float*)d_in[2];
    const float* brel    = (const float*)d_in[3];
    const float* Wroot   = (const float*)d_in[4];
    const float* gamma   = (const float*)d_in[5];
    const float* beta    = (const float*)d_in[6];
    float* out = (float*)d_out;

    char* ws = (char*)d_ws;
    size_t off = 0;
    int* col = (int*)(ws + off);           off = align256(off + (size_t)N_EDGES * 4);
    int* row_ptr = (int*)(ws + off);       off = align256(off + (size_t)(N_NODES + 1) * 4);
    int* cursor = (int*)(ws + off);        off = align256(off + (size_t)N_NODES * 4);
    float* hA = (float*)(ws + off);        off = align256(off + (size_t)N_NODES * DIM * 4);
    float* hB = (float*)(ws + off);        off = align256(off + (size_t)N_NODES * DIM * 4);
    (void)ws_size; (void)in_sizes; (void)n_in; (void)out_size;

    const int* src = ei;
    const int* dst = ei + N_EDGES;

    // CSR build (deg accumulates in `cursor`, scan resets it to row starts)
    hipMemsetAsync(cursor, 0, (size_t)N_NODES * 4, stream);
    hist_kernel<<<(N_EDGES + 255) / 256, 256, 0, stream>>>(dst, cursor, N_EDGES);
    scan_kernel<<<1, 1024, 0, stream>>>(cursor, row_ptr, N_NODES);
    fill_kernel<<<(N_EDGES + 255) / 256, 256, 0, stream>>>(src, dst, cursor, col, N_EDGES);

    float* agg = out;            // reuse d_out as aggregation scratch
    const int pull_grid = (N_NODES + 3) / 4;
    const int gemm_grid = N_NODES / 16;   // 100000 / 16 = 6250 exact

    // layer 0
    pull_kernel<<<pull_grid, 256, 0, stream>>>(in_feat, row_ptr, col, agg, N_NODES);
    gemm_kernel<0><<<gemm_grid, 256, 0, stream>>>(agg, in_feat, Wrel, brel, Wroot, gamma, beta, hA);
    // layer 1
    pull_kernel<<<pull_grid, 256, 0, stream>>>(hA, row_ptr, col, agg, N_NODES);
    gemm_kernel<1><<<gemm_grid, 256, 0, stream>>>(agg, hA, Wrel + 1 * DIM * DIM, brel + 1 * DIM,
                                                  Wroot + 1 * DIM * DIM, gamma, beta, hB);
    // layer 2
    pull_kernel<<<pull_grid, 256, 0, stream>>>(hB, row_ptr, col, agg, N_NODES);
    gemm_kernel<1><<<gemm_grid, 256, 0, stream>>>(agg, hB, Wrel + 2 * DIM * DIM, brel + 2 * DIM,
                                                  Wroot + 2 * DIM * DIM, gamma, beta, hA);
    // layer 3 (output, plain conv) — reads agg rows from d_out, writes d_out
    pull_kernel<<<pull_grid, 256, 0, stream>>>(hA, row_ptr, col, agg, N_NODES);
    gemm_kernel<2><<<gemm_grid, 256, 0, stream>>>(agg, hA, Wrel + 3 * DIM * DIM, brel + 3 * DIM,
                                                  Wroot + 3 * DIM * DIM, gamma, beta, out);
}

// Round 2
// 686.379 us; speedup vs baseline: 2.1807x; 2.1807x over previous
//
#include <hip/hip_runtime.h>
#include <cstddef>

#define N_NODES 100000
#define N_PAD   100032          // padded to 64-row multiple
#define N_EDGES 1600000
#define DIM 128
#define LN_EPS 1e-5f

typedef short bf16x8 __attribute__((ext_vector_type(8)));
typedef float f32x4 __attribute__((ext_vector_type(4)));

__device__ __forceinline__ float bf2f(uint u) {
    union { uint i; float f; } c; c.i = u << 16; return c.f;
}
__device__ __forceinline__ ushort f2bf(float x) {
    union { float f; uint i; } c; c.f = x;
    uint r = c.i + 0x7fffu + ((c.i >> 16) & 1u);   // RNE
    return (ushort)(r >> 16);
}

// ---------------- CSR build ----------------

__global__ void hist_kernel(const int* __restrict__ dst, int* __restrict__ deg, int e) {
    int i = blockIdx.x * blockDim.x + threadIdx.x;
    if (i < e) atomicAdd(&deg[dst[i]], 1);
}

__global__ __launch_bounds__(1024) void scan_kernel(int* __restrict__ cursor,
                                                    int* __restrict__ row_ptr, int n) {
    __shared__ int wsum[16];
    __shared__ int woff[16];
    __shared__ int ctot_s;
    const int tid = threadIdx.x;
    const int lane = tid & 63;
    const int wid = tid >> 6;
    int carry = 0;
    for (int base = 0; base < n; base += 4096) {
        const int i0 = base + tid * 4;
        int v0 = (i0 + 0 < n) ? cursor[i0 + 0] : 0;
        int v1 = (i0 + 1 < n) ? cursor[i0 + 1] : 0;
        int v2 = (i0 + 2 < n) ? cursor[i0 + 2] : 0;
        int v3 = (i0 + 3 < n) ? cursor[i0 + 3] : 0;
        const int tsum = v0 + v1 + v2 + v3;
        int incl = tsum;
        #pragma unroll
        for (int off = 1; off < 64; off <<= 1) {
            int t = __shfl_up(incl, off);
            if (lane >= off) incl += t;
        }
        if (lane == 63) wsum[wid] = incl;
        __syncthreads();
        if (wid == 0) {
            int x = (lane < 16) ? wsum[lane] : 0;
            int inc2 = x;
            #pragma unroll
            for (int off = 1; off < 16; off <<= 1) {
                int t = __shfl_up(inc2, off);
                if (lane >= off) inc2 += t;
            }
            if (lane < 16) woff[lane] = inc2 - x;
            if (lane == 15) ctot_s = inc2;
        }
        __syncthreads();
        int e0 = carry + woff[wid] + (incl - tsum);
        int e1 = e0 + v0;
        int e2 = e1 + v1;
        int e3 = e2 + v2;
        if (i0 + 0 < n) { row_ptr[i0 + 0] = e0; cursor[i0 + 0] = e0; }
        if (i0 + 1 < n) { row_ptr[i0 + 1] = e1; cursor[i0 + 1] = e1; }
        if (i0 + 2 < n) { row_ptr[i0 + 2] = e2; cursor[i0 + 2] = e2; }
        if (i0 + 3 < n) { row_ptr[i0 + 3] = e3; cursor[i0 + 3] = e3; }
        carry += ctot_s;
        __syncthreads();
    }
    if (tid == 0) row_ptr[n] = carry;
}

__global__ void fill_kernel(const int* __restrict__ src, const int* __restrict__ dst,
                            int* __restrict__ cursor, int* __restrict__ col, int e) {
    int i = blockIdx.x * blockDim.x + threadIdx.x;
    if (i < e) {
        int p = atomicAdd(&cursor[dst[i]], 1);
        col[p] = src[i];
    }
}

// ---------------- f32 -> bf16 conversion (layer-0 input) ----------------

__global__ void cvt_kernel(const float* __restrict__ in, ushort* __restrict__ out) {
    int i = (blockIdx.x * blockDim.x + threadIdx.x) * 4;
    float4 v = *(const float4*)&in[i];
    uint2 r;
    r.x = (uint)f2bf(v.x) | ((uint)f2bf(v.y) << 16);
    r.y = (uint)f2bf(v.z) | ((uint)f2bf(v.w) << 16);
    *(uint2*)&out[i] = r;
}

// ---------------- weight prepack into MFMA B-fragment order ----------------
// B-frag (kstep, n): lane l holds B[k = kstep*32 + (l>>4)*8 + j][col = n*16 + (l&15)], j=0..7
// flat: Wp[layer*32768 + ((kstep*8+n)*64 + lane)*8 + j], bf16

__global__ void prepack_kernel(const float* __restrict__ Wrel, const float* __restrict__ Wroot,
                               ushort* __restrict__ Wp) {
    int t = blockIdx.x * blockDim.x + threadIdx.x;    // 16384 threads
    int layer = t >> 12;
    int tl = t & 4095;
    int frag = tl >> 6;
    int lane = tl & 63;
    int ks = frag >> 3, n = frag & 7;
    int c = n * 16 + (lane & 15);
    int k0 = ks * 32 + (lane >> 4) * 8;
    ushort tmp[8];
    #pragma unroll
    for (int j = 0; j < 8; ++j) {
        int kg = k0 + j;
        float w = (kg < 128) ? Wrel[layer * 16384 + kg * 128 + c]
                             : Wroot[layer * 16384 + (kg - 128) * 128 + c];
        tmp[j] = f2bf(w);
    }
    *(uint4*)&Wp[(size_t)t * 8] = *(const uint4*)tmp;
}

// ---------------- aggregation (pull, one wave per node, bf16) ----------------

__global__ __launch_bounds__(256) void pull_kernel(const uint* __restrict__ h,
                                                   const int* __restrict__ row_ptr,
                                                   const int* __restrict__ col,
                                                   uint* __restrict__ agg, int n) {
    const int wid = threadIdx.x >> 6;
    const int lane = threadIdx.x & 63;
    const int node = blockIdx.x * 4 + wid;
    if (node >= n) return;
    const int beg = row_ptr[node];
    const int end = row_ptr[node + 1];
    float x0 = 0, y0 = 0, x1 = 0, y1 = 0, x2 = 0, y2 = 0, x3 = 0, y3 = 0;
    int j = beg;
    for (; j + 4 <= end; j += 4) {
        int s0 = col[j + 0], s1 = col[j + 1], s2 = col[j + 2], s3 = col[j + 3];
        uint p0 = h[(size_t)s0 * 64 + lane];
        uint p1 = h[(size_t)s1 * 64 + lane];
        uint p2 = h[(size_t)s2 * 64 + lane];
        uint p3 = h[(size_t)s3 * 64 + lane];
        x0 += bf2f(p0 & 0xffffu); y0 += bf2f(p0 >> 16);
        x1 += bf2f(p1 & 0xffffu); y1 += bf2f(p1 >> 16);
        x2 += bf2f(p2 & 0xffffu); y2 += bf2f(p2 >> 16);
        x3 += bf2f(p3 & 0xffffu); y3 += bf2f(p3 >> 16);
    }
    for (; j < end; ++j) {
        uint p = h[(size_t)col[j] * 64 + lane];
        x0 += bf2f(p & 0xffffu); y0 += bf2f(p >> 16);
    }
    float ax = (x0 + x1) + (x2 + x3);
    float ay = (y0 + y1) + (y2 + y3);
    agg[(size_t)node * 64 + lane] = (uint)f2bf(ax) | ((uint)f2bf(ay) << 16);
}

// ---------------- MFMA GEMM + fused epilogue ----------------
// out_row = [agg_row | h_row](256, bf16) @ Wp(256x128, bf16)  + brel  [+h] [relu+LN]
// MODE 0: relu+LN -> bf16 out ; MODE 1: +residual, relu+LN -> bf16 ; MODE 2: plain -> f32

template <int MODE>
__global__ __launch_bounds__(256) void gemm_kernel(const ushort* __restrict__ aggb,
                                                   const ushort* __restrict__ hb,
                                                   const ushort* __restrict__ Wp,
                                                   const float* __restrict__ brel,
                                                   const float* __restrict__ gamma,
                                                   const float* __restrict__ beta,
                                                   ushort* __restrict__ outb,
                                                   float* __restrict__ outf) {
    __shared__ char sX[64 * 512];   // 64 rows x 256 bf16 (agg|h), XOR-swizzled
    const int tid = threadIdx.x;
    const int row0 = blockIdx.x * 64;

    // stage 64 rows: 32 chunks of 16B per row
    for (int c = tid; c < 2048; c += 256) {
        int r = c >> 5, cb = c & 31;
        const ushort* srcp = (cb < 16) ? &aggb[(size_t)(row0 + r) * 128 + cb * 8]
                                       : &hb[(size_t)(row0 + r) * 128 + (cb - 16) * 8];
        uint4 v = *(const uint4*)srcp;
        *(uint4*)&sX[r * 512 + ((cb * 16) ^ ((r & 7) << 4))] = v;
    }
    __syncthreads();

    const int lane = tid & 63;
    const int wv = tid >> 6;
    const int kg = lane >> 4;    // 0..3
    const int cl = lane & 15;
    const int ra = wv * 16 + cl;             // A-operand row for this lane
    const int abase = ra * 512 + kg * 16;
    const int aswz = (ra & 7) << 4;

    f32x4 acc[8];
    #pragma unroll
    for (int n = 0; n < 8; ++n) acc[n] = (f32x4){0.f, 0.f, 0.f, 0.f};

    const uint4* bp = (const uint4*)Wp + lane;
    #pragma unroll 2
    for (int ks = 0; ks < 8; ++ks) {
        bf16x8 a = *(const bf16x8*)&sX[(abase + ks * 64) ^ aswz];
        #pragma unroll
        for (int n = 0; n < 8; ++n) {
            bf16x8 b = *(const bf16x8*)&bp[(ks * 8 + n) * 64];
            acc[n] = __builtin_amdgcn_mfma_f32_16x16x32_bf16(a, b, acc[n], 0, 0, 0);
        }
    }

    // epilogue: C layout col = n*16 + (lane&15), row = wv*16 + (lane>>4)*4 + reg
    float bias[8], gg[8], bb[8];
    #pragma unroll
    for (int n = 0; n < 8; ++n) {
        int cn = n * 16 + cl;
        bias[n] = brel[cn];
        if (MODE != 2) { gg[n] = gamma[cn]; bb[n] = beta[cn]; }
    }

    #pragma unroll
    for (int reg = 0; reg < 4; ++reg) {
        const int r = wv * 16 + kg * 4 + reg;       // local row
        const size_t grow = (size_t)row0 + r;
        float v[8];
        float s = 0.f, q = 0.f;
        #pragma unroll
        for (int n = 0; n < 8; ++n) {
            float x = acc[n][reg] + bias[n];
            if (MODE == 1) {
                int cn = n * 16 + cl;
                ushort hu = *(const ushort*)&sX[r * 512 + ((256 + 2 * cn) ^ ((r & 7) << 4))];
                x += bf2f(hu);
            }
            if (MODE != 2) x = fmaxf(x, 0.f);
            v[n] = x; s += x; q += x * x;
        }
        if (MODE != 2) {
            #pragma unroll
            for (int m = 8; m >= 1; m >>= 1) { s += __shfl_xor(s, m); q += __shfl_xor(q, m); }
            float mu = s * (1.f / DIM);
            float var = q * (1.f / DIM) - mu * mu;
            float rinv = rsqrtf(var + LN_EPS);
            #pragma unroll
            for (int n = 0; n < 8; ++n) {
                float y = (v[n] - mu) * rinv * gg[n] + bb[n];
                outb[grow * DIM + n * 16 + cl] = f2bf(y);
            }
        } else {
            if (grow < N_NODES) {
                #pragma unroll
                for (int n = 0; n < 8; ++n) outf[grow * DIM + n * 16 + cl] = v[n];
            }
        }
    }
}

// ---------------- launch ----------------

static inline size_t align256(size_t x) { return (x + 255) & ~(size_t)255; }

extern "C" void kernel_launch(void* const* d_in, const int* in_sizes, int n_in,
                              void* d_out, int out_size, void* d_ws, size_t ws_size,
                              hipStream_t stream) {
    const float* in_feat = (const float*)d_in[0];
    const int*   ei      = (const int*)d_in[1];
    const float* Wrel    = (const float*)d_in[2];
    const float* brel    = (const float*)d_in[3];
    const float* Wroot   = (const float*)d_in[4];
    const float* gamma   = (const float*)d_in[5];
    const float* beta    = (const float*)d_in[6];
    float* out = (float*)d_out;

    char* ws = (char*)d_ws;
    size_t off = 0;
    int* col = (int*)(ws + off);        off = align256(off + (size_t)N_EDGES * 4);
    int* row_ptr = (int*)(ws + off);    off = align256(off + (size_t)(N_NODES + 1) * 4);
    ushort* x0 = (ushort*)(ws + off);   off = align256(off + (size_t)N_PAD * DIM * 2);
    ushort* hA = (ushort*)(ws + off);   off = align256(off + (size_t)N_PAD * DIM * 2);
    ushort* hB = (ushort*)(ws + off);   off = align256(off + (size_t)N_PAD * DIM * 2);
    ushort* agg = (ushort*)(ws + off);  off = align256(off + (size_t)N_PAD * DIM * 2);
    ushort* Wp = (ushort*)(ws + off);   off = align256(off + (size_t)4 * 256 * 128 * 2);
    int* cursor = (int*)hB;             // hB not written until layer-1 gemm
    (void)ws_size; (void)in_sizes; (void)n_in; (void)out_size;

    const int* src = ei;
    const int* dst = ei + N_EDGES;

    // CSR build
    hipMemsetAsync(cursor, 0, (size_t)N_NODES * 4, stream);
    hist_kernel<<<(N_EDGES + 255) / 256, 256, 0, stream>>>(dst, cursor, N_EDGES);
    scan_kernel<<<1, 1024, 0, stream>>>(cursor, row_ptr, N_NODES);
    fill_kernel<<<(N_EDGES + 255) / 256, 256, 0, stream>>>(src, dst, cursor, col, N_EDGES);

    // zero pad rows (staging reads them; keeps MFMA inputs finite)
    const size_t padoff = (size_t)N_NODES * DIM * 2;
    const size_t padlen = (size_t)(N_PAD - N_NODES) * DIM * 2;
    hipMemsetAsync((char*)x0 + padoff, 0, padlen, stream);
    hipMemsetAsync((char*)agg + padoff, 0, padlen, stream);

    // input conversion + weight prepack
    cvt_kernel<<<(N_NODES * DIM) / (4 * 256), 256, 0, stream>>>(in_feat, x0);
    prepack_kernel<<<64, 256, 0, stream>>>(Wrel, Wroot, Wp);

    const int pull_grid = (N_NODES + 3) / 4;
    const int gemm_grid = N_PAD / 64;     // 1563

    // layer 0
    pull_kernel<<<pull_grid, 256, 0, stream>>>((const uint*)x0, row_ptr, col, (uint*)agg, N_NODES);
    gemm_kernel<0><<<gemm_grid, 256, 0, stream>>>(agg, x0, Wp, brel, gamma, beta, hA, nullptr);
    // layer 1
    pull_kernel<<<pull_grid, 256, 0, stream>>>((const uint*)hA, row_ptr, col, (uint*)agg, N_NODES);
    gemm_kernel<1><<<gemm_grid, 256, 0, stream>>>(agg, hA, Wp + 32768, brel + DIM, gamma, beta, hB, nullptr);
    // layer 2
    pull_kernel<<<pull_grid, 256, 0, stream>>>((const uint*)hB, row_ptr, col, (uint*)agg, N_NODES);
    gemm_kernel<1><<<gemm_grid, 256, 0, stream>>>(agg, hB, Wp + 2 * 32768, brel + 2 * DIM, gamma, beta, hA, nullptr);
    // layer 3 (plain conv, f32 output)
    pull_kernel<<<pull_grid, 256, 0, stream>>>((const uint*)hA, row_ptr, col, (uint*)agg, N_NODES);
    gemm_kernel<2><<<gemm_grid, 256, 0, stream>>>(agg, hA, Wp + 3 * 32768, brel + 3 * DIM, gamma, beta, nullptr, out);
}

// Round 3
// 468.629 us; speedup vs baseline: 3.1939x; 1.4647x over previous
//
#include <hip/hip_runtime.h>
#include <cstddef>

#define N_NODES 100000
#define N_PAD   100032          // padded to 64-row multiple
#define N_EDGES 1600000
#define DIM 128
#define LN_EPS 1e-5f

#define B_SHIFT 9
#define B_SIZE  512
#define N_BKT   196             // ceil(100032/512)
#define EPB     4096            // edges per block in bucket passes
#define NBLK    ((N_EDGES + EPB - 1) / EPB)   // 391

typedef short bf16x8 __attribute__((ext_vector_type(8)));
typedef float f32x4 __attribute__((ext_vector_type(4)));

__device__ __forceinline__ float asf(uint u) {
    union { uint i; float f; } c; c.i = u; return c.f;
}
__device__ __forceinline__ float bf2f(uint u) { return asf(u << 16); }
__device__ __forceinline__ ushort f2bf(float x) {
    union { float f; uint i; } c; c.f = x;
    uint r = c.i + 0x7fffu + ((c.i >> 16) & 1u);   // RNE
    return (ushort)(r >> 16);
}

// ================= bucketed CSR build =================
// bucket b = dst >> 9 (512 nodes per bucket, 196 buckets)

__global__ __launch_bounds__(256) void bhist_kernel(const int* __restrict__ dst,
                                                    int* __restrict__ bcount) {
    __shared__ int lh[N_BKT];
    const int tid = threadIdx.x;
    if (tid < N_BKT) lh[tid] = 0;
    __syncthreads();
    const int base = blockIdx.x * EPB;
    #pragma unroll
    for (int k = 0; k < 16; ++k) {
        int t = base + tid + k * 256;
        if (t < N_EDGES) atomicAdd(&lh[dst[t] >> B_SHIFT], 1);
    }
    __syncthreads();
    if (tid < N_BKT && lh[tid]) atomicAdd(&bcount[tid], lh[tid]);
}

__global__ __launch_bounds__(256) void bscan_kernel(const int* __restrict__ bcount,
                                                    int* __restrict__ bstart,
                                                    int* __restrict__ gcur) {
    __shared__ int s[256];
    const int tid = threadIdx.x;
    int v = (tid < N_BKT) ? bcount[tid] : 0;
    s[tid] = v;
    __syncthreads();
    for (int off = 1; off < 256; off <<= 1) {
        int t = (tid >= off) ? s[tid - off] : 0;
        __syncthreads();
        s[tid] += t;
        __syncthreads();
    }
    if (tid < N_BKT) { int e = s[tid] - v; bstart[tid] = e; gcur[tid] = e; }
    if (tid == 0) bstart[N_BKT] = N_EDGES;
}

__global__ __launch_bounds__(256) void bscatter_kernel(const int* __restrict__ src,
                                                       const int* __restrict__ dst,
                                                       int* __restrict__ gcur,
                                                       int2* __restrict__ pairs) {
    __shared__ int lcnt[N_BKT];
    __shared__ int lbase[N_BKT];
    const int tid = threadIdx.x;
    if (tid < N_BKT) lcnt[tid] = 0;
    __syncthreads();
    const int base = blockIdx.x * EPB;
    int ls[16], ld[16];
    #pragma unroll
    for (int k = 0; k < 16; ++k) {
        int t = base + tid + k * 256;
        if (t < N_EDGES) {
            ls[k] = src[t]; ld[k] = dst[t];
            atomicAdd(&lcnt[ld[k] >> B_SHIFT], 1);
        } else ld[k] = -1;
    }
    __syncthreads();
    if (tid < N_BKT) lbase[tid] = lcnt[tid] ? atomicAdd(&gcur[tid], lcnt[tid]) : 0;
    __syncthreads();
    if (tid < N_BKT) lcnt[tid] = 0;
    __syncthreads();
    #pragma unroll
    for (int k = 0; k < 16; ++k) {
        if (ld[k] >= 0) {
            int b = ld[k] >> B_SHIFT;
            int r = atomicAdd(&lcnt[b], 1);
            pairs[lbase[b] + r] = make_int2(ls[k], ld[k]);
        }
    }
}

// per-bucket degree count + fused exclusive scan -> row_ptr (absolute)
__global__ __launch_bounds__(256) void ndeg_kernel(const int2* __restrict__ pairs,
                                                   const int* __restrict__ bstart,
                                                   int* __restrict__ row_ptr) {
    __shared__ int ldeg[B_SIZE];
    __shared__ int ws[4];
    const int b = blockIdx.x;
    const int node0 = b << B_SHIFT;
    const int tid = threadIdx.x;
    ldeg[tid] = 0; ldeg[tid + 256] = 0;
    __syncthreads();
    const int beg = bstart[b], end = bstart[b + 1];
    for (int t = beg + tid; t < end; t += 256)
        atomicAdd(&ldeg[pairs[t].y - node0], 1);
    __syncthreads();
    const int d0 = ldeg[2 * tid], d1 = ldeg[2 * tid + 1];
    const int sum2 = d0 + d1;
    const int lane = tid & 63, wv = tid >> 6;
    int incl = sum2;
    #pragma unroll
    for (int off = 1; off < 64; off <<= 1) {
        int t = __shfl_up(incl, off);
        if (lane >= off) incl += t;
    }
    if (lane == 63) ws[wv] = incl;
    __syncthreads();
    int woff = 0;
    if (wv > 0) woff += ws[0];
    if (wv > 1) woff += ws[1];
    if (wv > 2) woff += ws[2];
    const int e0 = beg + woff + incl - sum2;
    const int n0 = node0 + 2 * tid;
    if (n0 < N_NODES)     row_ptr[n0]     = e0;
    if (n0 + 1 < N_NODES) row_ptr[n0 + 1] = e0 + d0;
    if (b == N_BKT - 1 && tid == 0) row_ptr[N_NODES] = N_EDGES;
}

__global__ __launch_bounds__(256) void bfill_kernel(const int2* __restrict__ pairs,
                                                    const int* __restrict__ bstart,
                                                    const int* __restrict__ row_ptr,
                                                    int* __restrict__ col) {
    __shared__ int lcur[B_SIZE];
    const int b = blockIdx.x;
    const int node0 = b << B_SHIFT;
    const int tid = threadIdx.x;
    #pragma unroll
    for (int k = 0; k < 2; ++k) {
        int n = node0 + tid + k * 256;
        lcur[tid + k * 256] = (n < N_NODES) ? row_ptr[n] : 0;
    }
    __syncthreads();
    const int beg = bstart[b], end = bstart[b + 1];
    for (int t = beg + tid; t < end; t += 256) {
        int2 p = pairs[t];
        int r = atomicAdd(&lcur[p.y - node0], 1);
        col[r] = p.x;
    }
}

// ================= f32 -> bf16 conversion =================

__global__ void cvt_kernel(const float* __restrict__ in, ushort* __restrict__ out) {
    int i = (blockIdx.x * blockDim.x + threadIdx.x) * 4;
    float4 v = *(const float4*)&in[i];
    uint2 r;
    r.x = (uint)f2bf(v.x) | ((uint)f2bf(v.y) << 16);
    r.y = (uint)f2bf(v.z) | ((uint)f2bf(v.w) << 16);
    *(uint2*)&out[i] = r;
}

// ================= weight prepack (MFMA B-fragment order) =================
// lane l holds B[k = ks*32 + (l>>4)*8 + j][col = n*16 + (l&15)], j=0..7

__global__ void prepack_kernel(const float* __restrict__ Wrel, const float* __restrict__ Wroot,
                               ushort* __restrict__ Wp) {
    int t = blockIdx.x * blockDim.x + threadIdx.x;    // 16384 threads
    int layer = t >> 12;
    int tl = t & 4095;
    int frag = tl >> 6;
    int lane = tl & 63;
    int ks = frag >> 3, n = frag & 7;
    int c = n * 16 + (lane & 15);
    int k0 = ks * 32 + (lane >> 4) * 8;
    ushort tmp[8];
    #pragma unroll
    for (int j = 0; j < 8; ++j) {
        int kg = k0 + j;
        float w = (kg < 128) ? Wrel[layer * 16384 + kg * 128 + c]
                             : Wroot[layer * 16384 + (kg - 128) * 128 + c];
        tmp[j] = f2bf(w);
    }
    *(uint4*)&Wp[(size_t)t * 8] = *(const uint4*)tmp;
}

// ================= aggregation (pull, 16B/lane => 4 rows per load) =================

__global__ __launch_bounds__(256) void pull_kernel(const uint4* __restrict__ h,
                                                   const int* __restrict__ row_ptr,
                                                   const int* __restrict__ col,
                                                   uint4* __restrict__ agg, int n) {
    const int wid = threadIdx.x >> 6;
    const int lane = threadIdx.x & 63;
    const int node = blockIdx.x * 4 + wid;
    if (node >= n) return;
    const int beg = row_ptr[node], end = row_ptr[node + 1];
    const int rsel = lane >> 4;         // which of 4 edges this lane-group loads
    const int c16 = lane & 15;          // 16B chunk within row
    float a0 = 0, a1 = 0, a2 = 0, a3 = 0, a4 = 0, a5 = 0, a6 = 0, a7 = 0;
    for (int j = beg; j < end; j += 4) {
        const int jj = j + rsel;
        const int s = col[jj < end ? jj : end - 1];
        uint4 p = h[(size_t)s * 16 + c16];
        if (jj < end) {
            a0 += asf(p.x << 16); a1 += asf(p.x & 0xffff0000u);
            a2 += asf(p.y << 16); a3 += asf(p.y & 0xffff0000u);
            a4 += asf(p.z << 16); a5 += asf(p.z & 0xffff0000u);
            a6 += asf(p.w << 16); a7 += asf(p.w & 0xffff0000u);
        }
    }
    a0 += __shfl_xor(a0, 16); a1 += __shfl_xor(a1, 16);
    a2 += __shfl_xor(a2, 16); a3 += __shfl_xor(a3, 16);
    a4 += __shfl_xor(a4, 16); a5 += __shfl_xor(a5, 16);
    a6 += __shfl_xor(a6, 16); a7 += __shfl_xor(a7, 16);
    a0 += __shfl_xor(a0, 32); a1 += __shfl_xor(a1, 32);
    a2 += __shfl_xor(a2, 32); a3 += __shfl_xor(a3, 32);
    a4 += __shfl_xor(a4, 32); a5 += __shfl_xor(a5, 32);
    a6 += __shfl_xor(a6, 32); a7 += __shfl_xor(a7, 32);
    if (rsel == 0) {
        uint4 o;
        o.x = (uint)f2bf(a0) | ((uint)f2bf(a1) << 16);
        o.y = (uint)f2bf(a2) | ((uint)f2bf(a3) << 16);
        o.z = (uint)f2bf(a4) | ((uint)f2bf(a5) << 16);
        o.w = (uint)f2bf(a6) | ((uint)f2bf(a7) << 16);
        agg[(size_t)node * 16 + c16] = o;
    }
}

// ================= MFMA GEMM + fused epilogue =================
// MODE 0: relu+LN -> bf16 ; MODE 1: +residual, relu+LN -> bf16 ; MODE 2: plain -> f32

template <int MODE>
__global__ __launch_bounds__(256) void gemm_kernel(const ushort* __restrict__ aggb,
                                                   const ushort* __restrict__ hb,
                                                   const ushort* __restrict__ Wp,
                                                   const float* __restrict__ brel,
                                                   const float* __restrict__ gamma,
                                                   const float* __restrict__ beta,
                                                   ushort* __restrict__ outb,
                                                   float* __restrict__ outf) {
    __shared__ char sX[64 * 512];   // 64 rows x 256 bf16 (agg|h), XOR-swizzled
    const int tid = threadIdx.x;
    const int row0 = blockIdx.x * 64;

    for (int c = tid; c < 2048; c += 256) {
        int r = c >> 5, cb = c & 31;
        const ushort* srcp = (cb < 16) ? &aggb[(size_t)(row0 + r) * 128 + cb * 8]
                                       : &hb[(size_t)(row0 + r) * 128 + (cb - 16) * 8];
        uint4 v = *(const uint4*)srcp;
        *(uint4*)&sX[r * 512 + ((cb * 16) ^ ((r & 7) << 4))] = v;
    }
    __syncthreads();

    const int lane = tid & 63;
    const int wv = tid >> 6;
    const int kg = lane >> 4;
    const int cl = lane & 15;
    const int ra = wv * 16 + cl;
    const int abase = ra * 512 + kg * 16;
    const int aswz = (ra & 7) << 4;

    f32x4 acc[8];
    #pragma unroll
    for (int n = 0; n < 8; ++n) acc[n] = (f32x4){0.f, 0.f, 0.f, 0.f};

    const uint4* bp = (const uint4*)Wp + lane;
    #pragma unroll 2
    for (int ks = 0; ks < 8; ++ks) {
        bf16x8 a = *(const bf16x8*)&sX[(abase + ks * 64) ^ aswz];
        #pragma unroll
        for (int n = 0; n < 8; ++n) {
            bf16x8 b = *(const bf16x8*)&bp[(ks * 8 + n) * 64];
            acc[n] = __builtin_amdgcn_mfma_f32_16x16x32_bf16(a, b, acc[n], 0, 0, 0);
        }
    }

    float bias[8], gg[8], bb[8];
    #pragma unroll
    for (int n = 0; n < 8; ++n) {
        int cn = n * 16 + cl;
        bias[n] = brel[cn];
        if (MODE != 2) { gg[n] = gamma[cn]; bb[n] = beta[cn]; }
    }

    #pragma unroll
    for (int reg = 0; reg < 4; ++reg) {
        const int r = wv * 16 + kg * 4 + reg;
        const size_t grow = (size_t)row0 + r;
        float v[8];
        float s = 0.f, q = 0.f;
        #pragma unroll
        for (int n = 0; n < 8; ++n) {
            float x = acc[n][reg] + bias[n];
            if (MODE == 1) {
                int cn = n * 16 + cl;
                ushort hu = *(const ushort*)&sX[r * 512 + ((256 + 2 * cn) ^ ((r & 7) << 4))];
                x += bf2f(hu);
            }
            if (MODE != 2) x = fmaxf(x, 0.f);
            v[n] = x; s += x; q += x * x;
        }
        if (MODE != 2) {
            #pragma unroll
            for (int m = 8; m >= 1; m >>= 1) { s += __shfl_xor(s, m); q += __shfl_xor(q, m); }
            float mu = s * (1.f / DIM);
            float var = q * (1.f / DIM) - mu * mu;
            float rinv = rsqrtf(var + LN_EPS);
            #pragma unroll
            for (int n = 0; n < 8; ++n) {
                float y = (v[n] - mu) * rinv * gg[n] + bb[n];
                outb[grow * DIM + n * 16 + cl] = f2bf(y);
            }
        } else {
            if (grow < N_NODES) {
                #pragma unroll
                for (int n = 0; n < 8; ++n) outf[grow * DIM + n * 16 + cl] = v[n];
            }
        }
    }
}

// ================= launch =================

static inline size_t align256(size_t x) { return (x + 255) & ~(size_t)255; }

extern "C" void kernel_launch(void* const* d_in, const int* in_sizes, int n_in,
                              void* d_out, int out_size, void* d_ws, size_t ws_size,
                              hipStream_t stream) {
    const float* in_feat = (const float*)d_in[0];
    const int*   ei      = (const int*)d_in[1];
    const float* Wrel    = (const float*)d_in[2];
    const float* brel    = (const float*)d_in[3];
    const float* Wroot   = (const float*)d_in[4];
    const float* gamma   = (const float*)d_in[5];
    const float* beta    = (const float*)d_in[6];
    float* out = (float*)d_out;

    char* ws = (char*)d_ws;
    size_t off = 0;
    int* col = (int*)(ws + off);        off = align256(off + (size_t)N_EDGES * 4);
    int2* pairs = (int2*)(ws + off);    off = align256(off + (size_t)N_EDGES * 8);
    int* row_ptr = (int*)(ws + off);    off = align256(off + (size_t)(N_NODES + 1) * 4);
    int* bcount = (int*)(ws + off);     off = align256(off + (size_t)N_BKT * 4);
    int* bstart = (int*)(ws + off);     off = align256(off + (size_t)(N_BKT + 1) * 4);
    int* gcur = (int*)(ws + off);       off = align256(off + (size_t)N_BKT * 4);
    ushort* x0 = (ushort*)(ws + off);   off = align256(off + (size_t)N_PAD * DIM * 2);
    ushort* hA = (ushort*)(ws + off);   off = align256(off + (size_t)N_PAD * DIM * 2);
    ushort* hB = (ushort*)(ws + off);   off = align256(off + (size_t)N_PAD * DIM * 2);
    ushort* agg = (ushort*)(ws + off);  off = align256(off + (size_t)N_PAD * DIM * 2);
    ushort* Wp = (ushort*)(ws + off);   off = align256(off + (size_t)4 * 256 * 128 * 2);
    (void)ws_size; (void)in_sizes; (void)n_in; (void)out_size;

    const int* src = ei;
    const int* dst = ei + N_EDGES;

    // bucketed CSR build
    hipMemsetAsync(bcount, 0, (size_t)N_BKT * 4, stream);
    bhist_kernel<<<NBLK, 256, 0, stream>>>(dst, bcount);
    bscan_kernel<<<1, 256, 0, stream>>>(bcount, bstart, gcur);
    bscatter_kernel<<<NBLK, 256, 0, stream>>>(src, dst, gcur, pairs);
    ndeg_kernel<<<N_BKT, 256, 0, stream>>>(pairs, bstart, row_ptr);
    bfill_kernel<<<N_BKT, 256, 0, stream>>>(pairs, bstart, row_ptr, col);

    // zero pad rows
    const size_t padoff = (size_t)N_NODES * DIM * 2;
    const size_t padlen = (size_t)(N_PAD - N_NODES) * DIM * 2;
    hipMemsetAsync((char*)x0 + padoff, 0, padlen, stream);
    hipMemsetAsync((char*)agg + padoff, 0, padlen, stream);

    // input conversion + weight prepack
    cvt_kernel<<<(N_NODES * DIM) / (4 * 256), 256, 0, stream>>>(in_feat, x0);
    prepack_kernel<<<64, 256, 0, stream>>>(Wrel, Wroot, Wp);

    const int pull_grid = (N_NODES + 3) / 4;
    const int gemm_grid = N_PAD / 64;

    // layer 0
    pull_kernel<<<pull_grid, 256, 0, stream>>>((const uint4*)x0, row_ptr, col, (uint4*)agg, N_NODES);
    gemm_kernel<0><<<gemm_grid, 256, 0, stream>>>(agg, x0, Wp, brel, gamma, beta, hA, nullptr);
    // layer 1
    pull_kernel<<<pull_grid, 256, 0, stream>>>((const uint4*)hA, row_ptr, col, (uint4*)agg, N_NODES);
    gemm_kernel<1><<<gemm_grid, 256, 0, stream>>>(agg, hA, Wp + 32768, brel + DIM, gamma, beta, hB, nullptr);
    // layer 2
    pull_kernel<<<pull_grid, 256, 0, stream>>>((const uint4*)hB, row_ptr, col, (uint4*)agg, N_NODES);
    gemm_kernel<1><<<gemm_grid, 256, 0, stream>>>(agg, hB, Wp + 2 * 32768, brel + 2 * DIM, gamma, beta, hA, nullptr);
    // layer 3 (plain conv, f32 output)
    pull_kernel<<<pull_grid, 256, 0, stream>>>((const uint4*)hA, row_ptr, col, (uint4*)agg, N_NODES);
    gemm_kernel<2><<<gemm_grid, 256, 0, stream>>>(agg, hA, Wp + 3 * 32768, brel + 3 * DIM, gamma, beta, nullptr, out);
}

// Round 4
// 429.126 us; speedup vs baseline: 3.4879x; 1.0921x over previous
//
#include <hip/hip_runtime.h>
#include <cstddef>

#define N_NODES 100000
#define N_PAD   100032          // padded to 64-row multiple
#define N_EDGES 1600000
#define DIM 128
#define LN_EPS 1e-5f
#define ZROW   N_NODES          // dedicated all-zero feature row

#define B_SHIFT 9
#define B_SIZE  512
#define N_BKT   196             // ceil(100032/512)
#define EPB     4096            // edges per block in bucket passes
#define NBLK    ((N_EDGES + EPB - 1) / EPB)   // 391

typedef short bf16x8 __attribute__((ext_vector_type(8)));
typedef float f32x4 __attribute__((ext_vector_type(4)));

__device__ __forceinline__ float asf(uint u) {
    union { uint i; float f; } c; c.i = u; return c.f;
}
__device__ __forceinline__ float bf2f(uint u) { return asf(u << 16); }
__device__ __forceinline__ ushort f2bf(float x) {
    union { float f; uint i; } c; c.f = x;
    uint r = c.i + 0x7fffu + ((c.i >> 16) & 1u);   // RNE
    return (ushort)(r >> 16);
}

__device__ __forceinline__ void acc8(float* a, uint4 p) {
    a[0] += asf(p.x << 16); a[1] += asf(p.x & 0xffff0000u);
    a[2] += asf(p.y << 16); a[3] += asf(p.y & 0xffff0000u);
    a[4] += asf(p.z << 16); a[5] += asf(p.z & 0xffff0000u);
    a[6] += asf(p.w << 16); a[7] += asf(p.w & 0xffff0000u);
}

// ================= bucketed CSR build =================

__global__ __launch_bounds__(256) void bhist_kernel(const int* __restrict__ dst,
                                                    int* __restrict__ bcount) {
    __shared__ int lh[N_BKT];
    const int tid = threadIdx.x;
    if (tid < N_BKT) lh[tid] = 0;
    __syncthreads();
    const int base = blockIdx.x * EPB;
    #pragma unroll
    for (int k = 0; k < 16; ++k) {
        int t = base + tid + k * 256;
        if (t < N_EDGES) atomicAdd(&lh[dst[t] >> B_SHIFT], 1);
    }
    __syncthreads();
    if (tid < N_BKT && lh[tid]) atomicAdd(&bcount[tid], lh[tid]);
}

__global__ __launch_bounds__(256) void bscan_kernel(const int* __restrict__ bcount,
                                                    int* __restrict__ bstart,
                                                    int* __restrict__ gcur) {
    __shared__ int s[256];
    const int tid = threadIdx.x;
    int v = (tid < N_BKT) ? bcount[tid] : 0;
    s[tid] = v;
    __syncthreads();
    for (int off = 1; off < 256; off <<= 1) {
        int t = (tid >= off) ? s[tid - off] : 0;
        __syncthreads();
        s[tid] += t;
        __syncthreads();
    }
    if (tid < N_BKT) { int e = s[tid] - v; bstart[tid] = e; gcur[tid] = e; }
    if (tid == 0) bstart[N_BKT] = N_EDGES;
}

__global__ __launch_bounds__(256) void bscatter_kernel(const int* __restrict__ src,
                                                       const int* __restrict__ dst,
                                                       int* __restrict__ gcur,
                                                       int2* __restrict__ pairs) {
    __shared__ int lcnt[N_BKT];
    __shared__ int lbase[N_BKT];
    const int tid = threadIdx.x;
    if (tid < N_BKT) lcnt[tid] = 0;
    __syncthreads();
    const int base = blockIdx.x * EPB;
    int ls[16], ld[16];
    #pragma unroll
    for (int k = 0; k < 16; ++k) {
        int t = base + tid + k * 256;
        if (t < N_EDGES) {
            ls[k] = src[t]; ld[k] = dst[t];
            atomicAdd(&lcnt[ld[k] >> B_SHIFT], 1);
        } else ld[k] = -1;
    }
    __syncthreads();
    if (tid < N_BKT) lbase[tid] = lcnt[tid] ? atomicAdd(&gcur[tid], lcnt[tid]) : 0;
    __syncthreads();
    if (tid < N_BKT) lcnt[tid] = 0;
    __syncthreads();
    #pragma unroll
    for (int k = 0; k < 16; ++k) {
        if (ld[k] >= 0) {
            int b = ld[k] >> B_SHIFT;
            int r = atomicAdd(&lcnt[b], 1);
            pairs[lbase[b] + r] = make_int2(ls[k], ld[k]);
        }
    }
}

__global__ __launch_bounds__(256) void ndeg_kernel(const int2* __restrict__ pairs,
                                                   const int* __restrict__ bstart,
                                                   int* __restrict__ row_ptr) {
    __shared__ int ldeg[B_SIZE];
    __shared__ int ws[4];
    const int b = blockIdx.x;
    const int node0 = b << B_SHIFT;
    const int tid = threadIdx.x;
    ldeg[tid] = 0; ldeg[tid + 256] = 0;
    __syncthreads();
    const int beg = bstart[b], end = bstart[b + 1];
    for (int t = beg + tid; t < end; t += 256)
        atomicAdd(&ldeg[pairs[t].y - node0], 1);
    __syncthreads();
    const int d0 = ldeg[2 * tid], d1 = ldeg[2 * tid + 1];
    const int sum2 = d0 + d1;
    const int lane = tid & 63, wv = tid >> 6;
    int incl = sum2;
    #pragma unroll
    for (int off = 1; off < 64; off <<= 1) {
        int t = __shfl_up(incl, off);
        if (lane >= off) incl += t;
    }
    if (lane == 63) ws[wv] = incl;
    __syncthreads();
    int woff = 0;
    if (wv > 0) woff += ws[0];
    if (wv > 1) woff += ws[1];
    if (wv > 2) woff += ws[2];
    const int e0 = beg + woff + incl - sum2;
    const int n0 = node0 + 2 * tid;
    if (n0 < N_NODES)     row_ptr[n0]     = e0;
    if (n0 + 1 < N_NODES) row_ptr[n0 + 1] = e0 + d0;
    if (b == N_BKT - 1 && tid == 0) row_ptr[N_NODES] = N_EDGES;
}

__global__ __launch_bounds__(256) void bfill_kernel(const int2* __restrict__ pairs,
                                                    const int* __restrict__ bstart,
                                                    const int* __restrict__ row_ptr,
                                                    int* __restrict__ col) {
    __shared__ int lcur[B_SIZE];
    const int b = blockIdx.x;
    const int node0 = b << B_SHIFT;
    const int tid = threadIdx.x;
    #pragma unroll
    for (int k = 0; k < 2; ++k) {
        int n = node0 + tid + k * 256;
        lcur[tid + k * 256] = (n < N_NODES) ? row_ptr[n] : 0;
    }
    __syncthreads();
    const int beg = bstart[b], end = bstart[b + 1];
    for (int t = beg + tid; t < end; t += 256) {
        int2 p = pairs[t];
        int r = atomicAdd(&lcur[p.y - node0], 1);
        col[r] = p.x;
    }
}

// ================= f32 -> bf16 conversion =================

__global__ void cvt_kernel(const float* __restrict__ in, ushort* __restrict__ out) {
    int i = (blockIdx.x * blockDim.x + threadIdx.x) * 4;
    float4 v = *(const float4*)&in[i];
    uint2 r;
    r.x = (uint)f2bf(v.x) | ((uint)f2bf(v.y) << 16);
    r.y = (uint)f2bf(v.z) | ((uint)f2bf(v.w) << 16);
    *(uint2*)&out[i] = r;
}

// ================= weight prepack (MFMA B-fragment order) =================

__global__ void prepack_kernel(const float* __restrict__ Wrel, const float* __restrict__ Wroot,
                               ushort* __restrict__ Wp) {
    int t = blockIdx.x * blockDim.x + threadIdx.x;    // 16384 threads
    int layer = t >> 12;
    int tl = t & 4095;
    int frag = tl >> 6;
    int lane = tl & 63;
    int ks = frag >> 3, n = frag & 7;
    int c = n * 16 + (lane & 15);
    int k0 = ks * 32 + (lane >> 4) * 8;
    ushort tmp[8];
    #pragma unroll
    for (int j = 0; j < 8; ++j) {
        int kg = k0 + j;
        float w = (kg < 128) ? Wrel[layer * 16384 + kg * 128 + c]
                             : Wroot[layer * 16384 + (kg - 128) * 128 + c];
        tmp[j] = f2bf(w);
    }
    *(uint4*)&Wp[(size_t)t * 8] = *(const uint4*)tmp;
}

// ================= aggregation (pull, 4 gathers in flight) =================

__global__ __launch_bounds__(256) void pull_kernel(const uint4* __restrict__ h,
                                                   const int* __restrict__ row_ptr,
                                                   const int* __restrict__ col,
                                                   uint4* __restrict__ agg, int n) {
    const int wid = threadIdx.x >> 6;
    const int lane = threadIdx.x & 63;
    const int node = blockIdx.x * 4 + wid;
    if (node >= n) return;
    const int beg = row_ptr[node], end = row_ptr[node + 1];
    const int rsel = lane >> 4;
    const int c16 = lane & 15;
    float a[8] = {0, 0, 0, 0, 0, 0, 0, 0};
    float b[8] = {0, 0, 0, 0, 0, 0, 0, 0};
    for (int j = beg; j < end; j += 16) {
        const int j0 = j + rsel, j1 = j0 + 4, j2 = j0 + 8, j3 = j0 + 12;
        const int last = end - 1;
        int s0 = col[min(j0, last)]; s0 = (j0 < end) ? s0 : ZROW;
        int s1 = col[min(j1, last)]; s1 = (j1 < end) ? s1 : ZROW;
        int s2 = col[min(j2, last)]; s2 = (j2 < end) ? s2 : ZROW;
        int s3 = col[min(j3, last)]; s3 = (j3 < end) ? s3 : ZROW;
        uint4 p0 = h[(size_t)s0 * 16 + c16];
        uint4 p1 = h[(size_t)s1 * 16 + c16];
        uint4 p2 = h[(size_t)s2 * 16 + c16];
        uint4 p3 = h[(size_t)s3 * 16 + c16];
        acc8(a, p0);
        acc8(b, p1);
        acc8(a, p2);
        acc8(b, p3);
    }
    #pragma unroll
    for (int u = 0; u < 8; ++u) {
        float v = a[u] + b[u];
        v += __shfl_xor(v, 16);
        v += __shfl_xor(v, 32);
        a[u] = v;
    }
    if (rsel == 0) {
        uint4 o;
        o.x = (uint)f2bf(a[0]) | ((uint)f2bf(a[1]) << 16);
        o.y = (uint)f2bf(a[2]) | ((uint)f2bf(a[3]) << 16);
        o.z = (uint)f2bf(a[4]) | ((uint)f2bf(a[5]) << 16);
        o.w = (uint)f2bf(a[6]) | ((uint)f2bf(a[7]) << 16);
        agg[(size_t)node * 16 + c16] = o;
    }
}

// ================= MFMA GEMM + fused epilogue =================
// MODE 0: relu+LN -> bf16 ; MODE 1: +residual, relu+LN -> bf16 ; MODE 2: plain -> f32
// Pad rows (grow >= N_NODES) are never stored: hA/hB pads stay zero (ZROW trick).

template <int MODE>
__global__ __launch_bounds__(256) void gemm_kernel(const ushort* __restrict__ aggb,
                                                   const ushort* __restrict__ hb,
                                                   const ushort* __restrict__ Wp,
                                                   const float* __restrict__ brel,
                                                   const float* __restrict__ gamma,
                                                   const float* __restrict__ beta,
                                                   ushort* __restrict__ outb,
                                                   float* __restrict__ outf) {
    __shared__ char sX[64 * 512];   // 64 rows x 256 bf16 (agg|h), XOR-swizzled
    const int tid = threadIdx.x;
    const int row0 = blockIdx.x * 64;

    for (int c = tid; c < 2048; c += 256) {
        int r = c >> 5, cb = c & 31;
        const ushort* srcp = (cb < 16) ? &aggb[(size_t)(row0 + r) * 128 + cb * 8]
                                       : &hb[(size_t)(row0 + r) * 128 + (cb - 16) * 8];
        uint4 v = *(const uint4*)srcp;
        *(uint4*)&sX[r * 512 + ((cb * 16) ^ ((r & 7) << 4))] = v;
    }
    __syncthreads();

    const int lane = tid & 63;
    const int wv = tid >> 6;
    const int kg = lane >> 4;
    const int cl = lane & 15;
    const int ra = wv * 16 + cl;
    const int abase = ra * 512 + kg * 16;
    const int aswz = (ra & 7) << 4;

    f32x4 acc[8];
    #pragma unroll
    for (int n = 0; n < 8; ++n) acc[n] = (f32x4){0.f, 0.f, 0.f, 0.f};

    const uint4* bp = (const uint4*)Wp + lane;
    #pragma unroll 2
    for (int ks = 0; ks < 8; ++ks) {
        bf16x8 a = *(const bf16x8*)&sX[(abase + ks * 64) ^ aswz];
        #pragma unroll
        for (int n = 0; n < 8; ++n) {
            bf16x8 b = *(const bf16x8*)&bp[(ks * 8 + n) * 64];
            acc[n] = __builtin_amdgcn_mfma_f32_16x16x32_bf16(a, b, acc[n], 0, 0, 0);
        }
    }

    float bias[8], gg[8], bb[8];
    #pragma unroll
    for (int n = 0; n < 8; ++n) {
        int cn = n * 16 + cl;
        bias[n] = brel[cn];
        if (MODE != 2) { gg[n] = gamma[cn]; bb[n] = beta[cn]; }
    }

    #pragma unroll
    for (int reg = 0; reg < 4; ++reg) {
        const int r = wv * 16 + kg * 4 + reg;
        const size_t grow = (size_t)row0 + r;
        const bool live = grow < N_NODES;
        float v[8];
        float s = 0.f, q = 0.f;
        #pragma unroll
        for (int n = 0; n < 8; ++n) {
            float x = acc[n][reg] + bias[n];
            if (MODE == 1) {
                int cn = n * 16 + cl;
                ushort hu = *(const ushort*)&sX[r * 512 + ((256 + 2 * cn) ^ ((r & 7) << 4))];
                x += bf2f(hu);
            }
            if (MODE != 2) x = fmaxf(x, 0.f);
            v[n] = x; s += x; q += x * x;
        }
        if (MODE != 2) {
            #pragma unroll
            for (int m = 8; m >= 1; m >>= 1) { s += __shfl_xor(s, m); q += __shfl_xor(q, m); }
            float mu = s * (1.f / DIM);
            float var = q * (1.f / DIM) - mu * mu;
            float rinv = rsqrtf(var + LN_EPS);
            if (live) {
                #pragma unroll
                for (int n = 0; n < 8; ++n) {
                    float y = (v[n] - mu) * rinv * gg[n] + bb[n];
                    outb[grow * DIM + n * 16 + cl] = f2bf(y);
                }
            }
        } else {
            if (live) {
                #pragma unroll
                for (int n = 0; n < 8; ++n) outf[grow * DIM + n * 16 + cl] = v[n];
            }
        }
    }
}

// ================= launch =================

static inline size_t align256(size_t x) { return (x + 255) & ~(size_t)255; }

extern "C" void kernel_launch(void* const* d_in, const int* in_sizes, int n_in,
                              void* d_out, int out_size, void* d_ws, size_t ws_size,
                              hipStream_t stream) {
    const float* in_feat = (const float*)d_in[0];
    const int*   ei      = (const int*)d_in[1];
    const float* Wrel    = (const float*)d_in[2];
    const float* brel    = (const float*)d_in[3];
    const float* Wroot   = (const float*)d_in[4];
    const float* gamma   = (const float*)d_in[5];
    const float* beta    = (const float*)d_in[6];
    float* out = (float*)d_out;

    char* ws = (char*)d_ws;
    size_t off = 0;
    int* col = (int*)(ws + off);        off = align256(off + (size_t)N_EDGES * 4);
    int2* pairs = (int2*)(ws + off);    off = align256(off + (size_t)N_EDGES * 8);
    int* row_ptr = (int*)(ws + off);    off = align256(off + (size_t)(N_NODES + 1) * 4);
    int* bcount = (int*)(ws + off);     off = align256(off + (size_t)N_BKT * 4);
    int* bstart = (int*)(ws + off);     off = align256(off + (size_t)(N_BKT + 1) * 4);
    int* gcur = (int*)(ws + off);       off = align256(off + (size_t)N_BKT * 4);
    ushort* x0 = (ushort*)(ws + off);   off = align256(off + (size_t)N_PAD * DIM * 2);
    ushort* hA = (ushort*)(ws + off);   off = align256(off + (size_t)N_PAD * DIM * 2);
    ushort* hB = (ushort*)(ws + off);   off = align256(off + (size_t)N_PAD * DIM * 2);
    ushort* agg = (ushort*)(ws + off);  off = align256(off + (size_t)N_PAD * DIM * 2);
    ushort* Wp = (ushort*)(ws + off);   off = align256(off + (size_t)4 * 256 * 128 * 2);
    (void)ws_size; (void)in_sizes; (void)n_in; (void)out_size;

    const int* src = ei;
    const int* dst = ei + N_EDGES;

    // bucketed CSR build
    hipMemsetAsync(bcount, 0, (size_t)N_BKT * 4, stream);
    bhist_kernel<<<NBLK, 256, 0, stream>>>(dst, bcount);
    bscan_kernel<<<1, 256, 0, stream>>>(bcount, bstart, gcur);
    bscatter_kernel<<<NBLK, 256, 0, stream>>>(src, dst, gcur, pairs);
    ndeg_kernel<<<N_BKT, 256, 0, stream>>>(pairs, bstart, row_ptr);
    bfill_kernel<<<N_BKT, 256, 0, stream>>>(pairs, bstart, row_ptr, col);

    // zero pad rows (ZROW trick requires pads of every feature buffer to be 0)
    const size_t padoff = (size_t)N_NODES * DIM * 2;
    const size_t padlen = (size_t)(N_PAD - N_NODES) * DIM * 2;
    hipMemsetAsync((char*)x0 + padoff, 0, padlen, stream);
    hipMemsetAsync((char*)hA + padoff, 0, padlen, stream);
    hipMemsetAsync((char*)hB + padoff, 0, padlen, stream);
    hipMemsetAsync((char*)agg + padoff, 0, padlen, stream);

    // input conversion + weight prepack
    cvt_kernel<<<(N_NODES * DIM) / (4 * 256), 256, 0, stream>>>(in_feat, x0);
    prepack_kernel<<<64, 256, 0, stream>>>(Wrel, Wroot, Wp);

    const int pull_grid = (N_NODES + 3) / 4;
    const int gemm_grid = N_PAD / 64;

    // layer 0
    pull_kernel<<<pull_grid, 256, 0, stream>>>((const uint4*)x0, row_ptr, col, (uint4*)agg, N_NODES);
    gemm_kernel<0><<<gemm_grid, 256, 0, stream>>>(agg, x0, Wp, brel, gamma, beta, hA, nullptr);
    // layer 1
    pull_kernel<<<pull_grid, 256, 0, stream>>>((const uint4*)hA, row_ptr, col, (uint4*)agg, N_NODES);
    gemm_kernel<1><<<gemm_grid, 256, 0, stream>>>(agg, hA, Wp + 32768, brel + DIM, gamma, beta, hB, nullptr);
    // layer 2
    pull_kernel<<<pull_grid, 256, 0, stream>>>((const uint4*)hB, row_ptr, col, (uint4*)agg, N_NODES);
    gemm_kernel<1><<<gemm_grid, 256, 0, stream>>>(agg, hB, Wp + 2 * 32768, brel + 2 * DIM, gamma, beta, hA, nullptr);
    // layer 3 (plain conv, f32 output)
    pull_kernel<<<pull_grid, 256, 0, stream>>>((const uint4*)hA, row_ptr, col, (uint4*)agg, N_NODES);
    gemm_kernel<2><<<gemm_grid, 256, 0, stream>>>(agg, hA, Wp + 3 * 32768, brel + 3 * DIM, gamma, beta, nullptr, out);
}